// Round 4
// baseline (547.082 us; speedup 1.0000x reference)
//
#include <hip/hip_runtime.h>

// ---------------------------------------------------------------------------
// GraphConv x2 (DGL norm='both', self-loops), fp32 baseline (r4).
// Pipeline: degrees -> norms+scan (fused) -> CSR(dst) -> [GEMM+scale -> agg] x2
// ---------------------------------------------------------------------------

__global__ __launch_bounds__(256) void k_hist(const int* __restrict__ src,
                                              const int* __restrict__ dst,
                                              int* __restrict__ odeg,
                                              int* __restrict__ ideg, int E) {
  int e = blockIdx.x * 256 + threadIdx.x;
  if (e < E) {
    atomicAdd(&odeg[src[e]], 1);
    atomicAdd(&ideg[dst[e]], 1);
  }
}

// exclusive scan of in-degree -> rowptr partials; also emit rsqrt norms
__global__ __launch_bounds__(256) void k_scan1_norm(
    const int* __restrict__ ideg, const int* __restrict__ odeg,
    int* __restrict__ part, int* __restrict__ bsums,
    float* __restrict__ nsrc, float* __restrict__ ndst, int N) {
  __shared__ int s[256];
  int t = threadIdx.x, g = blockIdx.x * 256 + t;
  int v = (g < N) ? ideg[g] : 0;
  if (g < N) {
    nsrc[g] = rsqrtf((float)(odeg[g] + 1)); // +1 self-loop, deg>=1
    ndst[g] = rsqrtf((float)(v + 1));
  }
  s[t] = v;
  __syncthreads();
  for (int o = 1; o < 256; o <<= 1) {
    int add = (t >= o) ? s[t - o] : 0;
    __syncthreads();
    s[t] += add;
    __syncthreads();
  }
  if (g < N) part[g] = s[t] - v;            // exclusive within block
  if (t == 255) bsums[blockIdx.x] = s[255]; // block total
}

// NOTE: requires gridDim of k_scan1_norm (= ceil(N/256)) <= 256.
// N=50000 -> 196 blocks. OK.
__global__ __launch_bounds__(256) void k_scan2(int* __restrict__ bsums, int nb) {
  __shared__ int s[256];
  int t = threadIdx.x;
  int v = (t < nb) ? bsums[t] : 0;
  s[t] = v;
  __syncthreads();
  for (int o = 1; o < 256; o <<= 1) {
    int add = (t >= o) ? s[t - o] : 0;
    __syncthreads();
    s[t] += add;
    __syncthreads();
  }
  if (t < nb) bsums[t] = s[t] - v; // exclusive block offsets
}

__global__ __launch_bounds__(256) void k_scan3(int* __restrict__ part,
                                               int* __restrict__ cursor,
                                               const int* __restrict__ bsums,
                                               int N, int E) {
  int t = threadIdx.x, g = blockIdx.x * 256 + t;
  if (g < N) {
    int v = part[g] + bsums[blockIdx.x];
    part[g] = v;
    cursor[g] = v;
  }
  if (g == 0) part[N] = E;
}

__global__ __launch_bounds__(256) void k_fill(const int* __restrict__ src,
                                              const int* __restrict__ dst,
                                              int* __restrict__ cursor,
                                              int* __restrict__ colidx, int E) {
  int e = blockIdx.x * 256 + threadIdx.x;
  if (e < E) {
    int s = src[e]; // load operand before atomic so the store has it in flight
    int p = atomicAdd(&cursor[dst[e]], 1);
    colidx[p] = s;
  }
}

// out[m, :] = (A[m, :] @ W) * norm[m];  64x64 tile, BK=32, 4x4 micro-tile
__global__ __launch_bounds__(256) void k_gemm_scale(
    const float* __restrict__ A, const float* __restrict__ W,
    const float* __restrict__ norm, float* __restrict__ out,
    int M, int N, int K) {
  __shared__ float As[32][68]; // transposed [k][m], stride 68 keeps 16B align
  __shared__ float Ws[32][64]; // [k][n]
  int tid = threadIdx.x;
  int tx = tid & 15, ty = tid >> 4;
  int row0 = blockIdx.x * 64, col0 = blockIdx.y * 64;
  float c[4][4] = {};
  for (int k0 = 0; k0 < K; k0 += 32) {
#pragma unroll
    for (int i = 0; i < 2; ++i) { // A tile: 64 rows x 32 cols as float4
      int idx = tid + i * 256;
      int r = idx >> 3, c4 = idx & 7;
      int gr = row0 + r;
      float4 v = make_float4(0.f, 0.f, 0.f, 0.f);
      if (gr < M) v = *reinterpret_cast<const float4*>(&A[(size_t)gr * K + k0 + c4 * 4]);
      As[c4 * 4 + 0][r] = v.x;
      As[c4 * 4 + 1][r] = v.y;
      As[c4 * 4 + 2][r] = v.z;
      As[c4 * 4 + 3][r] = v.w;
    }
#pragma unroll
    for (int i = 0; i < 2; ++i) { // W tile: 32 rows x 64 cols as float4
      int idx = tid + i * 256;
      int r = idx >> 4, c4 = idx & 15;
      float4 v = *reinterpret_cast<const float4*>(&W[(size_t)(k0 + r) * N + col0 + c4 * 4]);
      *reinterpret_cast<float4*>(&Ws[r][c4 * 4]) = v;
    }
    __syncthreads();
#pragma unroll
    for (int kk = 0; kk < 32; ++kk) {
      float4 a = *reinterpret_cast<const float4*>(&As[kk][ty * 4]);
      float4 w = *reinterpret_cast<const float4*>(&Ws[kk][tx * 4]);
      c[0][0] = fmaf(a.x, w.x, c[0][0]); c[0][1] = fmaf(a.x, w.y, c[0][1]);
      c[0][2] = fmaf(a.x, w.z, c[0][2]); c[0][3] = fmaf(a.x, w.w, c[0][3]);
      c[1][0] = fmaf(a.y, w.x, c[1][0]); c[1][1] = fmaf(a.y, w.y, c[1][1]);
      c[1][2] = fmaf(a.y, w.z, c[1][2]); c[1][3] = fmaf(a.y, w.w, c[1][3]);
      c[2][0] = fmaf(a.z, w.x, c[2][0]); c[2][1] = fmaf(a.z, w.y, c[2][1]);
      c[2][2] = fmaf(a.z, w.z, c[2][2]); c[2][3] = fmaf(a.z, w.w, c[2][3]);
      c[3][0] = fmaf(a.w, w.x, c[3][0]); c[3][1] = fmaf(a.w, w.y, c[3][1]);
      c[3][2] = fmaf(a.w, w.z, c[3][2]); c[3][3] = fmaf(a.w, w.w, c[3][3]);
    }
    __syncthreads();
  }
#pragma unroll
  for (int i = 0; i < 4; ++i) {
    int gr = row0 + ty * 4 + i;
    if (gr < M) {
      float s = norm[gr];
      float4 v;
      v.x = c[i][0] * s; v.y = c[i][1] * s; v.z = c[i][2] * s; v.w = c[i][3] * s;
      *reinterpret_cast<float4*>(&out[(size_t)gr * N + col0 + tx * 4]) = v;
    }
  }
}

// pull aggregation, C=256: one wave per node, lane owns 4 channels (float4).
// 4-edge unroll: 4 independent 1KB row-gathers in flight per wave.
__global__ __launch_bounds__(256) void k_agg256(
    const float* __restrict__ h, const int* __restrict__ rowptr,
    const int* __restrict__ colidx, const float* __restrict__ nd,
    const float* __restrict__ bias, float* __restrict__ out, int N) {
  int node = blockIdx.x * 4 + (threadIdx.x >> 6);
  int lane = threadIdx.x & 63;
  if (node >= N) return;
  const float4* hv = reinterpret_cast<const float4*>(h);
  float4 acc = hv[(size_t)node * 64 + lane]; // self-loop
  int e0 = rowptr[node], e1 = rowptr[node + 1];
  int e = e0;
  for (; e + 3 < e1; e += 4) {
    int s0 = colidx[e], s1 = colidx[e + 1], s2 = colidx[e + 2], s3 = colidx[e + 3];
    float4 v0 = hv[(size_t)s0 * 64 + lane];
    float4 v1 = hv[(size_t)s1 * 64 + lane];
    float4 v2 = hv[(size_t)s2 * 64 + lane];
    float4 v3 = hv[(size_t)s3 * 64 + lane];
    acc.x += (v0.x + v1.x) + (v2.x + v3.x);
    acc.y += (v0.y + v1.y) + (v2.y + v3.y);
    acc.z += (v0.z + v1.z) + (v2.z + v3.z);
    acc.w += (v0.w + v1.w) + (v2.w + v3.w);
  }
  for (; e < e1; ++e) {
    float4 v0 = hv[(size_t)colidx[e] * 64 + lane];
    acc.x += v0.x; acc.y += v0.y; acc.z += v0.z; acc.w += v0.w;
  }
  float n = nd[node];
  float4 b = reinterpret_cast<const float4*>(bias)[lane];
  float4 r;
  r.x = fmaxf(fmaf(acc.x, n, b.x), 0.f);
  r.y = fmaxf(fmaf(acc.y, n, b.y), 0.f);
  r.z = fmaxf(fmaf(acc.z, n, b.z), 0.f);
  r.w = fmaxf(fmaf(acc.w, n, b.w), 0.f);
  reinterpret_cast<float4*>(out)[(size_t)node * 64 + lane] = r;
}

// pull aggregation, C=128: one wave per node, lane owns 2 channels (float2)
__global__ __launch_bounds__(256) void k_agg128(
    const float* __restrict__ h, const int* __restrict__ rowptr,
    const int* __restrict__ colidx, const float* __restrict__ nd,
    const float* __restrict__ bias, float* __restrict__ out, int N) {
  int node = blockIdx.x * 4 + (threadIdx.x >> 6);
  int lane = threadIdx.x & 63;
  if (node >= N) return;
  const float2* hv = reinterpret_cast<const float2*>(h);
  float2 acc = hv[(size_t)node * 64 + lane]; // self-loop
  int e0 = rowptr[node], e1 = rowptr[node + 1];
  int e = e0;
  for (; e + 3 < e1; e += 4) {
    int s0 = colidx[e], s1 = colidx[e + 1], s2 = colidx[e + 2], s3 = colidx[e + 3];
    float2 v0 = hv[(size_t)s0 * 64 + lane];
    float2 v1 = hv[(size_t)s1 * 64 + lane];
    float2 v2 = hv[(size_t)s2 * 64 + lane];
    float2 v3 = hv[(size_t)s3 * 64 + lane];
    acc.x += (v0.x + v1.x) + (v2.x + v3.x);
    acc.y += (v0.y + v1.y) + (v2.y + v3.y);
  }
  for (; e < e1; ++e) {
    float2 v0 = hv[(size_t)colidx[e] * 64 + lane];
    acc.x += v0.x; acc.y += v0.y;
  }
  float n = nd[node];
  float2 b = reinterpret_cast<const float2*>(bias)[lane];
  float2 r;
  r.x = fmaxf(fmaf(acc.x, n, b.x), 0.f);
  r.y = fmaxf(fmaf(acc.y, n, b.y), 0.f);
  reinterpret_cast<float2*>(out)[(size_t)node * 64 + lane] = r;
}

extern "C" void kernel_launch(void* const* d_in, const int* in_sizes, int n_in,
                              void* d_out, int out_size, void* d_ws, size_t ws_size,
                              hipStream_t stream) {
  const float* feats = (const float*)d_in[0];
  const int* src = (const int*)d_in[1];
  const int* dst = (const int*)d_in[2];
  const float* W0 = (const float*)d_in[3];
  const float* b0 = (const float*)d_in[4];
  const float* W1 = (const float*)d_in[5];
  const float* b1 = (const float*)d_in[6];
  float* out = (float*)d_out;

  const int IN_CH = 256, HID = 256, OUT_CH = 128;
  int N = in_sizes[0] / IN_CH;
  int E = in_sizes[1];

  char* ws = (char*)d_ws;
  size_t off = 0;
  auto alloc = [&](size_t bytes) -> void* {
    void* p = ws + off;
    off += (bytes + 255) & ~(size_t)255;
    return p;
  };
  float* h0     = (float*)alloc((size_t)N * HID * 4);   // layer-0 GEMM out
  float* x1     = (float*)alloc((size_t)N * HID * 4);   // layer-0 agg out
  float* nsrc   = (float*)alloc((size_t)N * 4);
  float* ndst   = (float*)alloc((size_t)N * 4);
  size_t degBytes = ((size_t)N * 4 + 255) & ~(size_t)255;
  int*   odeg   = (int*)alloc(degBytes * 2);            // odeg|ideg contiguous
  int*   ideg   = (int*)((char*)odeg + degBytes);
  int*   rowptr = (int*)alloc((size_t)(N + 1) * 4);
  int*   cursor = (int*)alloc((size_t)N * 4);
  int*   colidx = (int*)alloc((size_t)E * 4);
  int*   bsums  = (int*)alloc(1024);
  float* h1     = h0; // reuse: h0 is dead after k_agg256 (layer-1 GEMM out)

  hipMemsetAsync(odeg, 0, degBytes * 2, stream); // zeroes odeg AND ideg

  int nbE = (E + 255) / 256, nbN = (N + 255) / 256;
  k_hist<<<nbE, 256, 0, stream>>>(src, dst, odeg, ideg, E);
  k_scan1_norm<<<nbN, 256, 0, stream>>>(ideg, odeg, rowptr, bsums, nsrc, ndst, N);
  k_scan2<<<1, 256, 0, stream>>>(bsums, nbN);
  k_scan3<<<nbN, 256, 0, stream>>>(rowptr, cursor, bsums, N, E);
  k_fill<<<nbE, 256, 0, stream>>>(src, dst, cursor, colidx, E);

  dim3 g0((N + 63) / 64, HID / 64);
  k_gemm_scale<<<g0, 256, 0, stream>>>(feats, W0, nsrc, h0, N, HID, IN_CH);
  k_agg256<<<(N + 3) / 4, 256, 0, stream>>>(h0, rowptr, colidx, ndst, b0, x1, N);

  dim3 g1((N + 63) / 64, OUT_CH / 64);
  k_gemm_scale<<<g1, 256, 0, stream>>>(x1, W1, nsrc, h1, N, OUT_CH, HID);
  k_agg128<<<(N + 3) / 4, 256, 0, stream>>>(h1, rowptr, colidx, ndst, b1, out, N);
}

// Round 6
// 483.188 us; speedup vs baseline: 1.1322x; 1.1322x over previous
//
#include <hip/hip_runtime.h>

// ---------------------------------------------------------------------------
// GraphConv x2 (DGL norm='both', self-loops), r6 (= r5 re-audited, never ran).
// degrees -> norms+scan -> CSR(dst) -> [MFMA-split GEMM+scale -> pull-agg] x2
// GEMM: fp32 emulated as bf16 hi/lo split, 3x mfma_f32_16x16x32_bf16 (hh,hl,lh)
// ---------------------------------------------------------------------------

typedef __attribute__((ext_vector_type(8))) short short8v;
typedef __attribute__((ext_vector_type(4))) float float4v;

__device__ inline unsigned short f2bf(float x) {
  unsigned u = __float_as_uint(x);
  return (unsigned short)((u + 0x7FFFu + ((u >> 16) & 1u)) >> 16);
}
__device__ inline float bf2f(unsigned short b) {
  return __uint_as_float(((unsigned)b) << 16);
}

__global__ __launch_bounds__(256) void k_hist(const int* __restrict__ src,
                                              const int* __restrict__ dst,
                                              int* __restrict__ odeg,
                                              int* __restrict__ ideg, int E) {
  int e = blockIdx.x * 256 + threadIdx.x;
  if (e < E) {
    atomicAdd(&odeg[src[e]], 1);
    atomicAdd(&ideg[dst[e]], 1);
  }
}

// exclusive scan of in-degree -> rowptr partials; also emit rsqrt norms
__global__ __launch_bounds__(256) void k_scan1_norm(
    const int* __restrict__ ideg, const int* __restrict__ odeg,
    int* __restrict__ part, int* __restrict__ bsums,
    float* __restrict__ nsrc, float* __restrict__ ndst, int N) {
  __shared__ int s[256];
  int t = threadIdx.x, g = blockIdx.x * 256 + t;
  int v = (g < N) ? ideg[g] : 0;
  if (g < N) {
    nsrc[g] = rsqrtf((float)(odeg[g] + 1)); // +1 self-loop, deg>=1
    ndst[g] = rsqrtf((float)(v + 1));
  }
  s[t] = v;
  __syncthreads();
  for (int o = 1; o < 256; o <<= 1) {
    int add = (t >= o) ? s[t - o] : 0;
    __syncthreads();
    s[t] += add;
    __syncthreads();
  }
  if (g < N) part[g] = s[t] - v;
  if (t == 255) bsums[blockIdx.x] = s[255];
}

// requires ceil(N/256) <= 256 (N=50000 -> 196 blocks, OK)
__global__ __launch_bounds__(256) void k_scan2(int* __restrict__ bsums, int nb) {
  __shared__ int s[256];
  int t = threadIdx.x;
  int v = (t < nb) ? bsums[t] : 0;
  s[t] = v;
  __syncthreads();
  for (int o = 1; o < 256; o <<= 1) {
    int add = (t >= o) ? s[t - o] : 0;
    __syncthreads();
    s[t] += add;
    __syncthreads();
  }
  if (t < nb) bsums[t] = s[t] - v;
}

__global__ __launch_bounds__(256) void k_scan3(int* __restrict__ part,
                                               int* __restrict__ cursor,
                                               const int* __restrict__ bsums,
                                               int N, int E) {
  int t = threadIdx.x, g = blockIdx.x * 256 + t;
  if (g < N) {
    int v = part[g] + bsums[blockIdx.x];
    part[g] = v;
    cursor[g] = v;
  }
  if (g == 0) part[N] = E;
}

__global__ __launch_bounds__(256) void k_fill(const int* __restrict__ src,
                                              const int* __restrict__ dst,
                                              int* __restrict__ cursor,
                                              int* __restrict__ colidx, int E) {
  int e = blockIdx.x * 256 + threadIdx.x;
  if (e < E) {
    int s = src[e];
    int p = atomicAdd(&cursor[dst[e]], 1);
    colidx[p] = s;
  }
}

// W [K][NCOL] fp32 -> WtH/WtL [NCOL][K] bf16 (transposed + hi/lo split). K=256.
__global__ __launch_bounds__(256) void k_wsplit(const float* __restrict__ W,
                                                short* __restrict__ WtH,
                                                short* __restrict__ WtL,
                                                int NCOL) {
  const int K = 256;
  int idx = blockIdx.x * 256 + threadIdx.x;
  if (idx >= K * NCOL) return;
  int k = idx & (K - 1);
  int n = idx >> 8;
  float v = W[(size_t)k * NCOL + n];
  unsigned short h = f2bf(v);
  unsigned short l = f2bf(v - bf2f(h));
  WtH[(size_t)n * K + k] = (short)h;
  WtL[(size_t)n * K + k] = (short)l;
}

// out[m,:] = (A[m,:] @ W) * norm[m]; A fp32 [M][256], W pre-split [NCOL][256].
// BM=64 rows/block, full NCOL width (A read exactly once). 4 waves: wave w
// owns rows w*16..w*16+15. bf16 hi/lo split -> 3 MFMA (hh, hl, lh) per tile.
// A/B fragments use the same (lane,k) map, so any within-K HW permutation
// cancels; D map col=lane&15, row=(lane>>4)*4+j (m89-verified).
template <int NCOL>
__global__ __launch_bounds__(256) void k_gemm_mfma(
    const float* __restrict__ A, const short* __restrict__ WtH,
    const short* __restrict__ WtL, const float* __restrict__ norm,
    float* __restrict__ out, int M) {
  constexpr int K = 256, BM = 64, BK = 32, PAD = 40, NF = NCOL / 16;
  __shared__ short AH[BM][PAD], AL[BM][PAD];
  __shared__ short BH[NCOL][PAD], BL[NCOL][PAD];
  int tid = threadIdx.x;
  int w = tid >> 6, l = tid & 63;
  int lg = l >> 4, ln = l & 15;
  int row0 = blockIdx.x * BM;

  float4v acc[NF];
#pragma unroll
  for (int i = 0; i < NF; ++i) acc[i] = (float4v){0.f, 0.f, 0.f, 0.f};

  int ar = tid >> 2;        // A-stage row 0..63
  int akq = (tid & 3) * 8;  // A-stage k offset 0/8/16/24

  for (int k0 = 0; k0 < K; k0 += BK) {
    // ---- stage A tile: fp32 -> bf16 hi/lo ----
    float av[8];
    int grow = row0 + ar;
    if (grow < M) {
      const float4* ap =
          reinterpret_cast<const float4*>(&A[(size_t)grow * K + k0 + akq]);
      float4 v0 = ap[0], v1 = ap[1];
      av[0] = v0.x; av[1] = v0.y; av[2] = v0.z; av[3] = v0.w;
      av[4] = v1.x; av[5] = v1.y; av[6] = v1.z; av[7] = v1.w;
    } else {
#pragma unroll
      for (int i = 0; i < 8; ++i) av[i] = 0.f;
    }
    short hh[8], ll[8];
#pragma unroll
    for (int i = 0; i < 8; ++i) {
      unsigned short h = f2bf(av[i]);
      hh[i] = (short)h;
      ll[i] = (short)f2bf(av[i] - bf2f(h));
    }
    *reinterpret_cast<short8v*>(&AH[ar][akq]) = *reinterpret_cast<short8v*>(hh);
    *reinterpret_cast<short8v*>(&AL[ar][akq]) = *reinterpret_cast<short8v*>(ll);

    // ---- stage B tile: NCOL rows x 32 k, bf16 pre-split, 16B chunks ----
#pragma unroll
    for (int c = 0; c < NCOL / 64; ++c) {
      int chunk = c * 256 + tid;
      int bn = chunk >> 2, q = (chunk & 3) * 8;
      *reinterpret_cast<short8v*>(&BH[bn][q]) =
          *reinterpret_cast<const short8v*>(&WtH[(size_t)bn * K + k0 + q]);
      *reinterpret_cast<short8v*>(&BL[bn][q]) =
          *reinterpret_cast<const short8v*>(&WtL[(size_t)bn * K + k0 + q]);
    }
    __syncthreads();

    // ---- MFMA ----
    short8v aH = *reinterpret_cast<short8v*>(&AH[w * 16 + ln][lg * 8]);
    short8v aL = *reinterpret_cast<short8v*>(&AL[w * 16 + ln][lg * 8]);
#pragma unroll
    for (int nf = 0; nf < NF; ++nf) {
      short8v bHv = *reinterpret_cast<short8v*>(&BH[nf * 16 + ln][lg * 8]);
      short8v bLv = *reinterpret_cast<short8v*>(&BL[nf * 16 + ln][lg * 8]);
      acc[nf] = __builtin_amdgcn_mfma_f32_16x16x32_bf16(aH, bHv, acc[nf], 0, 0, 0);
      acc[nf] = __builtin_amdgcn_mfma_f32_16x16x32_bf16(aH, bLv, acc[nf], 0, 0, 0);
      acc[nf] = __builtin_amdgcn_mfma_f32_16x16x32_bf16(aL, bHv, acc[nf], 0, 0, 0);
    }
    __syncthreads();
  }

  // ---- epilogue: scale by norm[row], store fp32 ----
  int rbase = row0 + w * 16 + lg * 4;
  float nrm[4];
#pragma unroll
  for (int j = 0; j < 4; ++j)
    nrm[j] = (rbase + j < M) ? norm[rbase + j] : 0.f;
#pragma unroll
  for (int nf = 0; nf < NF; ++nf) {
#pragma unroll
    for (int j = 0; j < 4; ++j) {
      int r = rbase + j;
      if (r < M) out[(size_t)r * NCOL + nf * 16 + ln] = acc[nf][j] * nrm[j];
    }
  }
}

// pull aggregation, C=256: one wave/node, lane owns 4 ch (float4), 8 in flight
__global__ __launch_bounds__(256) void k_agg256(
    const float* __restrict__ h, const int* __restrict__ rowptr,
    const int* __restrict__ colidx, const float* __restrict__ nd,
    const float* __restrict__ bias, float* __restrict__ out, int N) {
  int node = blockIdx.x * 4 + (threadIdx.x >> 6);
  int lane = threadIdx.x & 63;
  if (node >= N) return;
  const float4* hv = reinterpret_cast<const float4*>(h);
  float4 acc = hv[(size_t)node * 64 + lane]; // self-loop
  int e0 = rowptr[node], e1 = rowptr[node + 1];
  int e = e0;
  for (; e + 7 < e1; e += 8) {
    int si[8];
#pragma unroll
    for (int i = 0; i < 8; ++i) si[i] = colidx[e + i];
    float4 v[8];
#pragma unroll
    for (int i = 0; i < 8; ++i) v[i] = hv[(size_t)si[i] * 64 + lane];
#pragma unroll
    for (int i = 0; i < 8; ++i) {
      acc.x += v[i].x; acc.y += v[i].y; acc.z += v[i].z; acc.w += v[i].w;
    }
  }
  for (; e < e1; ++e) {
    float4 v0 = hv[(size_t)colidx[e] * 64 + lane];
    acc.x += v0.x; acc.y += v0.y; acc.z += v0.z; acc.w += v0.w;
  }
  float n = nd[node];
  float4 b = reinterpret_cast<const float4*>(bias)[lane];
  float4 r;
  r.x = fmaxf(fmaf(acc.x, n, b.x), 0.f);
  r.y = fmaxf(fmaf(acc.y, n, b.y), 0.f);
  r.z = fmaxf(fmaf(acc.z, n, b.z), 0.f);
  r.w = fmaxf(fmaf(acc.w, n, b.w), 0.f);
  reinterpret_cast<float4*>(out)[(size_t)node * 64 + lane] = r;
}

// pull aggregation, C=128: one wave/node, lane owns 2 ch (float2), 8 in flight
__global__ __launch_bounds__(256) void k_agg128(
    const float* __restrict__ h, const int* __restrict__ rowptr,
    const int* __restrict__ colidx, const float* __restrict__ nd,
    const float* __restrict__ bias, float* __restrict__ out, int N) {
  int node = blockIdx.x * 4 + (threadIdx.x >> 6);
  int lane = threadIdx.x & 63;
  if (node >= N) return;
  const float2* hv = reinterpret_cast<const float2*>(h);
  float2 acc = hv[(size_t)node * 64 + lane]; // self-loop
  int e0 = rowptr[node], e1 = rowptr[node + 1];
  int e = e0;
  for (; e + 7 < e1; e += 8) {
    int si[8];
#pragma unroll
    for (int i = 0; i < 8; ++i) si[i] = colidx[e + i];
    float2 v[8];
#pragma unroll
    for (int i = 0; i < 8; ++i) v[i] = hv[(size_t)si[i] * 64 + lane];
#pragma unroll
    for (int i = 0; i < 8; ++i) { acc.x += v[i].x; acc.y += v[i].y; }
  }
  for (; e < e1; ++e) {
    float2 v0 = hv[(size_t)colidx[e] * 64 + lane];
    acc.x += v0.x; acc.y += v0.y;
  }
  float n = nd[node];
  float2 b = reinterpret_cast<const float2*>(bias)[lane];
  float2 r;
  r.x = fmaxf(fmaf(acc.x, n, b.x), 0.f);
  r.y = fmaxf(fmaf(acc.y, n, b.y), 0.f);
  reinterpret_cast<float2*>(out)[(size_t)node * 64 + lane] = r;
}

extern "C" void kernel_launch(void* const* d_in, const int* in_sizes, int n_in,
                              void* d_out, int out_size, void* d_ws, size_t ws_size,
                              hipStream_t stream) {
  const float* feats = (const float*)d_in[0];
  const int* src = (const int*)d_in[1];
  const int* dst = (const int*)d_in[2];
  const float* W0 = (const float*)d_in[3];
  const float* b0 = (const float*)d_in[4];
  const float* W1 = (const float*)d_in[5];
  const float* b1 = (const float*)d_in[6];
  float* out = (float*)d_out;

  const int IN_CH = 256, HID = 256, OUT_CH = 128;
  int N = in_sizes[0] / IN_CH;
  int E = in_sizes[1];

  char* ws = (char*)d_ws;
  size_t off = 0;
  auto alloc = [&](size_t bytes) -> void* {
    void* p = ws + off;
    off += (bytes + 255) & ~(size_t)255;
    return p;
  };
  float* h0     = (float*)alloc((size_t)N * HID * 4);   // layer-0 GEMM out
  float* x1     = (float*)alloc((size_t)N * HID * 4);   // layer-0 agg out
  float* nsrc   = (float*)alloc((size_t)N * 4);
  float* ndst   = (float*)alloc((size_t)N * 4);
  size_t degBytes = ((size_t)N * 4 + 255) & ~(size_t)255;
  int*   odeg   = (int*)alloc(degBytes * 2);            // odeg|ideg contiguous
  int*   ideg   = (int*)((char*)odeg + degBytes);
  int*   rowptr = (int*)alloc((size_t)(N + 1) * 4);
  int*   cursor = (int*)alloc((size_t)N * 4);
  int*   colidx = (int*)alloc((size_t)E * 4);
  int*   bsums  = (int*)alloc(1024);
  short* w0h    = (short*)alloc((size_t)HID * IN_CH * 2);
  short* w0l    = (short*)alloc((size_t)HID * IN_CH * 2);
  short* w1h    = (short*)alloc((size_t)OUT_CH * HID * 2);
  short* w1l    = (short*)alloc((size_t)OUT_CH * HID * 2);
  float* h1     = h0; // reuse: h0 dead after k_agg256

  hipMemsetAsync(odeg, 0, degBytes * 2, stream);

  int nbE = (E + 255) / 256, nbN = (N + 255) / 256;
  k_hist<<<nbE, 256, 0, stream>>>(src, dst, odeg, ideg, E);
  k_scan1_norm<<<nbN, 256, 0, stream>>>(ideg, odeg, rowptr, bsums, nsrc, ndst, N);
  k_scan2<<<1, 256, 0, stream>>>(bsums, nbN);
  k_scan3<<<nbN, 256, 0, stream>>>(rowptr, cursor, bsums, N, E);
  k_fill<<<nbE, 256, 0, stream>>>(src, dst, cursor, colidx, E);

  // weight transpose + bf16 split (K=256 for both layers)
  k_wsplit<<<(IN_CH * HID) / 256, 256, 0, stream>>>(W0, w0h, w0l, HID);
  k_wsplit<<<(HID * OUT_CH) / 256, 256, 0, stream>>>(W1, w1h, w1l, OUT_CH);

  int gm = (N + 63) / 64;
  k_gemm_mfma<256><<<gm, 256, 0, stream>>>(feats, w0h, w0l, nsrc, h0, N);
  k_agg256<<<(N + 3) / 4, 256, 0, stream>>>(h0, rowptr, colidx, ndst, b0, x1, N);

  k_gemm_mfma<128><<<gm, 256, 0, stream>>>(x1, w1h, w1l, nsrc, h1, N);
  k_agg128<<<(N + 3) / 4, 256, 0, stream>>>(h1, rowptr, colidx, ndst, b1, out, N);
}

// Round 7
// 404.503 us; speedup vs baseline: 1.3525x; 1.1945x over previous
//
#include <hip/hip_runtime.h>

// ---------------------------------------------------------------------------
// GraphConv x2 (DGL norm='both', self-loops), r7.
// degrees -> norms+scan -> CSR(dst) -> [MFMA-split GEMM+scale -> pull-agg] x2
// GEMM: fp32 emulated as bf16 hi/lo split, 3x mfma_f32_16x16x32_bf16 (hh,hl,lh)
// NEW r7: gathered arrays h0/h1 stored fp16 (halves agg HBM traffic; fp16 RN
// err 2^-11 on |h|<~2 adds ~3e-4 absmax). x1 (GEMM input) stays fp32.
// ---------------------------------------------------------------------------

typedef __attribute__((ext_vector_type(8))) short short8v;
typedef __attribute__((ext_vector_type(4))) float float4v;
typedef __attribute__((ext_vector_type(4))) _Float16 half4v;
typedef __attribute__((ext_vector_type(2))) _Float16 half2v;

__device__ inline unsigned short f2bf(float x) {
  unsigned u = __float_as_uint(x);
  return (unsigned short)((u + 0x7FFFu + ((u >> 16) & 1u)) >> 16);
}
__device__ inline float bf2f(unsigned short b) {
  return __uint_as_float(((unsigned)b) << 16);
}

__global__ __launch_bounds__(256) void k_hist(const int* __restrict__ src,
                                              const int* __restrict__ dst,
                                              int* __restrict__ odeg,
                                              int* __restrict__ ideg, int E) {
  int e = blockIdx.x * 256 + threadIdx.x;
  if (e < E) {
    atomicAdd(&odeg[src[e]], 1);
    atomicAdd(&ideg[dst[e]], 1);
  }
}

// exclusive scan of in-degree -> rowptr partials; also emit rsqrt norms
__global__ __launch_bounds__(256) void k_scan1_norm(
    const int* __restrict__ ideg, const int* __restrict__ odeg,
    int* __restrict__ part, int* __restrict__ bsums,
    float* __restrict__ nsrc, float* __restrict__ ndst, int N) {
  __shared__ int s[256];
  int t = threadIdx.x, g = blockIdx.x * 256 + t;
  int v = (g < N) ? ideg[g] : 0;
  if (g < N) {
    nsrc[g] = rsqrtf((float)(odeg[g] + 1)); // +1 self-loop, deg>=1
    ndst[g] = rsqrtf((float)(v + 1));
  }
  s[t] = v;
  __syncthreads();
  for (int o = 1; o < 256; o <<= 1) {
    int add = (t >= o) ? s[t - o] : 0;
    __syncthreads();
    s[t] += add;
    __syncthreads();
  }
  if (g < N) part[g] = s[t] - v;
  if (t == 255) bsums[blockIdx.x] = s[255];
}

// requires ceil(N/256) <= 256 (N=50000 -> 196 blocks, OK)
__global__ __launch_bounds__(256) void k_scan2(int* __restrict__ bsums, int nb) {
  __shared__ int s[256];
  int t = threadIdx.x;
  int v = (t < nb) ? bsums[t] : 0;
  s[t] = v;
  __syncthreads();
  for (int o = 1; o < 256; o <<= 1) {
    int add = (t >= o) ? s[t - o] : 0;
    __syncthreads();
    s[t] += add;
    __syncthreads();
  }
  if (t < nb) bsums[t] = s[t] - v;
}

__global__ __launch_bounds__(256) void k_scan3(int* __restrict__ part,
                                               int* __restrict__ cursor,
                                               const int* __restrict__ bsums,
                                               int N, int E) {
  int t = threadIdx.x, g = blockIdx.x * 256 + t;
  if (g < N) {
    int v = part[g] + bsums[blockIdx.x];
    part[g] = v;
    cursor[g] = v;
  }
  if (g == 0) part[N] = E;
}

__global__ __launch_bounds__(256) void k_fill(const int* __restrict__ src,
                                              const int* __restrict__ dst,
                                              int* __restrict__ cursor,
                                              int* __restrict__ colidx, int E) {
  int e = blockIdx.x * 256 + threadIdx.x;
  if (e < E) {
    int s = src[e];
    int p = atomicAdd(&cursor[dst[e]], 1);
    colidx[p] = s;
  }
}

// W [K][NCOL] fp32 -> WtH/WtL [NCOL][K] bf16 (transposed + hi/lo split). K=256.
__global__ __launch_bounds__(256) void k_wsplit(const float* __restrict__ W,
                                                short* __restrict__ WtH,
                                                short* __restrict__ WtL,
                                                int NCOL) {
  const int K = 256;
  int idx = blockIdx.x * 256 + threadIdx.x;
  if (idx >= K * NCOL) return;
  int k = idx & (K - 1);
  int n = idx >> 8;
  float v = W[(size_t)k * NCOL + n];
  unsigned short h = f2bf(v);
  unsigned short l = f2bf(v - bf2f(h));
  WtH[(size_t)n * K + k] = (short)h;
  WtL[(size_t)n * K + k] = (short)l;
}

// out[m,:] = fp16((A[m,:] @ W) * norm[m]); A fp32 [M][256], W pre-split.
// BM=64 rows/block, full NCOL width (A read exactly once). 4 waves: wave w
// owns rows w*16..w*16+15. bf16 hi/lo split -> 3 MFMA (hh, hl, lh) per tile.
// A/B fragments use the same (lane,k) map, so any within-K HW permutation
// cancels; D map col=lane&15, row=(lane>>4)*4+j (m89-verified).
template <int NCOL>
__global__ __launch_bounds__(256) void k_gemm_mfma(
    const float* __restrict__ A, const short* __restrict__ WtH,
    const short* __restrict__ WtL, const float* __restrict__ norm,
    _Float16* __restrict__ out, int M) {
  constexpr int K = 256, BM = 64, BK = 32, PAD = 40, NF = NCOL / 16;
  __shared__ short AH[BM][PAD], AL[BM][PAD];
  __shared__ short BH[NCOL][PAD], BL[NCOL][PAD];
  int tid = threadIdx.x;
  int w = tid >> 6, l = tid & 63;
  int lg = l >> 4, ln = l & 15;
  int row0 = blockIdx.x * BM;

  float4v acc[NF];
#pragma unroll
  for (int i = 0; i < NF; ++i) acc[i] = (float4v){0.f, 0.f, 0.f, 0.f};

  int ar = tid >> 2;        // A-stage row 0..63
  int akq = (tid & 3) * 8;  // A-stage k offset 0/8/16/24

  for (int k0 = 0; k0 < K; k0 += BK) {
    // ---- stage A tile: fp32 -> bf16 hi/lo ----
    float av[8];
    int grow = row0 + ar;
    if (grow < M) {
      const float4* ap =
          reinterpret_cast<const float4*>(&A[(size_t)grow * K + k0 + akq]);
      float4 v0 = ap[0], v1 = ap[1];
      av[0] = v0.x; av[1] = v0.y; av[2] = v0.z; av[3] = v0.w;
      av[4] = v1.x; av[5] = v1.y; av[6] = v1.z; av[7] = v1.w;
    } else {
#pragma unroll
      for (int i = 0; i < 8; ++i) av[i] = 0.f;
    }
    short hh[8], ll[8];
#pragma unroll
    for (int i = 0; i < 8; ++i) {
      unsigned short h = f2bf(av[i]);
      hh[i] = (short)h;
      ll[i] = (short)f2bf(av[i] - bf2f(h));
    }
    *reinterpret_cast<short8v*>(&AH[ar][akq]) = *reinterpret_cast<short8v*>(hh);
    *reinterpret_cast<short8v*>(&AL[ar][akq]) = *reinterpret_cast<short8v*>(ll);

    // ---- stage B tile: NCOL rows x 32 k, bf16 pre-split, 16B chunks ----
#pragma unroll
    for (int c = 0; c < NCOL / 64; ++c) {
      int chunk = c * 256 + tid;
      int bn = chunk >> 2, q = (chunk & 3) * 8;
      *reinterpret_cast<short8v*>(&BH[bn][q]) =
          *reinterpret_cast<const short8v*>(&WtH[(size_t)bn * K + k0 + q]);
      *reinterpret_cast<short8v*>(&BL[bn][q]) =
          *reinterpret_cast<const short8v*>(&WtL[(size_t)bn * K + k0 + q]);
    }
    __syncthreads();

    // ---- MFMA ----
    short8v aH = *reinterpret_cast<short8v*>(&AH[w * 16 + ln][lg * 8]);
    short8v aL = *reinterpret_cast<short8v*>(&AL[w * 16 + ln][lg * 8]);
#pragma unroll
    for (int nf = 0; nf < NF; ++nf) {
      short8v bHv = *reinterpret_cast<short8v*>(&BH[nf * 16 + ln][lg * 8]);
      short8v bLv = *reinterpret_cast<short8v*>(&BL[nf * 16 + ln][lg * 8]);
      acc[nf] = __builtin_amdgcn_mfma_f32_16x16x32_bf16(aH, bHv, acc[nf], 0, 0, 0);
      acc[nf] = __builtin_amdgcn_mfma_f32_16x16x32_bf16(aH, bLv, acc[nf], 0, 0, 0);
      acc[nf] = __builtin_amdgcn_mfma_f32_16x16x32_bf16(aL, bHv, acc[nf], 0, 0, 0);
    }
    __syncthreads();
  }

  // ---- epilogue: scale by norm[row], store fp16 ----
  int rbase = row0 + w * 16 + lg * 4;
  float nrm[4];
#pragma unroll
  for (int j = 0; j < 4; ++j)
    nrm[j] = (rbase + j < M) ? norm[rbase + j] : 0.f;
#pragma unroll
  for (int nf = 0; nf < NF; ++nf) {
#pragma unroll
    for (int j = 0; j < 4; ++j) {
      int r = rbase + j;
      if (r < M)
        out[(size_t)r * NCOL + nf * 16 + ln] = (_Float16)(acc[nf][j] * nrm[j]);
    }
  }
}

// pull aggregation, C=256: one wave/node, lane owns 4 ch (fp16 gather, fp32 acc)
__global__ __launch_bounds__(256) void k_agg256(
    const _Float16* __restrict__ h, const int* __restrict__ rowptr,
    const int* __restrict__ colidx, const float* __restrict__ nd,
    const float* __restrict__ bias, float* __restrict__ out, int N) {
  int node = blockIdx.x * 4 + (threadIdx.x >> 6);
  int lane = threadIdx.x & 63;
  if (node >= N) return;
  const half4v* hv = reinterpret_cast<const half4v*>(h);
  half4v hs = hv[(size_t)node * 64 + lane]; // self-loop
  float4 acc;
  acc.x = (float)hs[0]; acc.y = (float)hs[1];
  acc.z = (float)hs[2]; acc.w = (float)hs[3];
  int e0 = rowptr[node], e1 = rowptr[node + 1];
  int e = e0;
  for (; e + 7 < e1; e += 8) {
    int si[8];
#pragma unroll
    for (int i = 0; i < 8; ++i) si[i] = colidx[e + i];
    half4v v[8];
#pragma unroll
    for (int i = 0; i < 8; ++i) v[i] = hv[(size_t)si[i] * 64 + lane];
#pragma unroll
    for (int i = 0; i < 8; ++i) {
      acc.x += (float)v[i][0]; acc.y += (float)v[i][1];
      acc.z += (float)v[i][2]; acc.w += (float)v[i][3];
    }
  }
  for (; e < e1; ++e) {
    half4v v0 = hv[(size_t)colidx[e] * 64 + lane];
    acc.x += (float)v0[0]; acc.y += (float)v0[1];
    acc.z += (float)v0[2]; acc.w += (float)v0[3];
  }
  float n = nd[node];
  float4 b = reinterpret_cast<const float4*>(bias)[lane];
  float4 r;
  r.x = fmaxf(fmaf(acc.x, n, b.x), 0.f);
  r.y = fmaxf(fmaf(acc.y, n, b.y), 0.f);
  r.z = fmaxf(fmaf(acc.z, n, b.z), 0.f);
  r.w = fmaxf(fmaf(acc.w, n, b.w), 0.f);
  reinterpret_cast<float4*>(out)[(size_t)node * 64 + lane] = r;
}

// pull aggregation, C=128: one wave/node, lane owns 2 ch (fp16 gather, fp32 acc)
__global__ __launch_bounds__(256) void k_agg128(
    const _Float16* __restrict__ h, const int* __restrict__ rowptr,
    const int* __restrict__ colidx, const float* __restrict__ nd,
    const float* __restrict__ bias, float* __restrict__ out, int N) {
  int node = blockIdx.x * 4 + (threadIdx.x >> 6);
  int lane = threadIdx.x & 63;
  if (node >= N) return;
  const half2v* hv = reinterpret_cast<const half2v*>(h);
  half2v hs = hv[(size_t)node * 64 + lane]; // self-loop
  float2 acc;
  acc.x = (float)hs[0]; acc.y = (float)hs[1];
  int e0 = rowptr[node], e1 = rowptr[node + 1];
  int e = e0;
  for (; e + 7 < e1; e += 8) {
    int si[8];
#pragma unroll
    for (int i = 0; i < 8; ++i) si[i] = colidx[e + i];
    half2v v[8];
#pragma unroll
    for (int i = 0; i < 8; ++i) v[i] = hv[(size_t)si[i] * 64 + lane];
#pragma unroll
    for (int i = 0; i < 8; ++i) {
      acc.x += (float)v[i][0]; acc.y += (float)v[i][1];
    }
  }
  for (; e < e1; ++e) {
    half2v v0 = hv[(size_t)colidx[e] * 64 + lane];
    acc.x += (float)v0[0]; acc.y += (float)v0[1];
  }
  float n = nd[node];
  float2 b = reinterpret_cast<const float2*>(bias)[lane];
  float2 r;
  r.x = fmaxf(fmaf(acc.x, n, b.x), 0.f);
  r.y = fmaxf(fmaf(acc.y, n, b.y), 0.f);
  reinterpret_cast<float2*>(out)[(size_t)node * 64 + lane] = r;
}

extern "C" void kernel_launch(void* const* d_in, const int* in_sizes, int n_in,
                              void* d_out, int out_size, void* d_ws, size_t ws_size,
                              hipStream_t stream) {
  const float* feats = (const float*)d_in[0];
  const int* src = (const int*)d_in[1];
  const int* dst = (const int*)d_in[2];
  const float* W0 = (const float*)d_in[3];
  const float* b0 = (const float*)d_in[4];
  const float* W1 = (const float*)d_in[5];
  const float* b1 = (const float*)d_in[6];
  float* out = (float*)d_out;

  const int IN_CH = 256, HID = 256, OUT_CH = 128;
  int N = in_sizes[0] / IN_CH;
  int E = in_sizes[1];

  char* ws = (char*)d_ws;
  size_t off = 0;
  auto alloc = [&](size_t bytes) -> void* {
    void* p = ws + off;
    off += (bytes + 255) & ~(size_t)255;
    return p;
  };
  _Float16* h0 = (_Float16*)alloc((size_t)N * HID * 2); // layer-0 GEMM out, fp16
  float* x1     = (float*)alloc((size_t)N * HID * 4);   // layer-0 agg out, fp32
  float* nsrc   = (float*)alloc((size_t)N * 4);
  float* ndst   = (float*)alloc((size_t)N * 4);
  size_t degBytes = ((size_t)N * 4 + 255) & ~(size_t)255;
  int*   odeg   = (int*)alloc(degBytes * 2);            // odeg|ideg contiguous
  int*   ideg   = (int*)((char*)odeg + degBytes);
  int*   rowptr = (int*)alloc((size_t)(N + 1) * 4);
  int*   cursor = (int*)alloc((size_t)N * 4);
  int*   colidx = (int*)alloc((size_t)E * 4);
  int*   bsums  = (int*)alloc(1024);
  short* w0h    = (short*)alloc((size_t)HID * IN_CH * 2);
  short* w0l    = (short*)alloc((size_t)HID * IN_CH * 2);
  short* w1h    = (short*)alloc((size_t)OUT_CH * HID * 2);
  short* w1l    = (short*)alloc((size_t)OUT_CH * HID * 2);
  _Float16* h1  = h0; // reuse: h0 dead after k_agg256 (12.8MB <= 25.6MB)

  hipMemsetAsync(odeg, 0, degBytes * 2, stream);

  int nbE = (E + 255) / 256, nbN = (N + 255) / 256;
  k_hist<<<nbE, 256, 0, stream>>>(src, dst, odeg, ideg, E);
  k_scan1_norm<<<nbN, 256, 0, stream>>>(ideg, odeg, rowptr, bsums, nsrc, ndst, N);
  k_scan2<<<1, 256, 0, stream>>>(bsums, nbN);
  k_scan3<<<nbN, 256, 0, stream>>>(rowptr, cursor, bsums, N, E);
  k_fill<<<nbE, 256, 0, stream>>>(src, dst, cursor, colidx, E);

  // weight transpose + bf16 split (K=256 for both layers)
  k_wsplit<<<(IN_CH * HID) / 256, 256, 0, stream>>>(W0, w0h, w0l, HID);
  k_wsplit<<<(HID * OUT_CH) / 256, 256, 0, stream>>>(W1, w1h, w1l, OUT_CH);

  int gm = (N + 63) / 64;
  k_gemm_mfma<256><<<gm, 256, 0, stream>>>(feats, w0h, w0l, nsrc, h0, N);
  k_agg256<<<(N + 3) / 4, 256, 0, stream>>>(h0, rowptr, colidx, ndst, b0, x1, N);

  k_gemm_mfma<128><<<gm, 256, 0, stream>>>(x1, w1h, w1l, nsrc, h1, N);
  k_agg128<<<(N + 3) / 4, 256, 0, stream>>>(h1, rowptr, colidx, ndst, b1, out, N);
}

// Round 8
// 398.318 us; speedup vs baseline: 1.3735x; 1.0155x over previous
//
#include <hip/hip_runtime.h>

// ---------------------------------------------------------------------------
// GraphConv x2 (DGL norm='both', self-loops), r8.
// degrees (per-XCD scoped atomics) -> norms+scan -> CSR(dst) ->
// [MFMA-split GEMM+scale -> pull-agg(fp16)] x2
// GEMM: fp32 emulated as bf16 hi/lo split, 3x mfma_f32_16x16x32_bf16
// r8 NEW: k_hist8 uses 8 per-XCD histogram copies + workgroup-scope atomics
// (stay in the XCD's L2; kills the 64B/atomic write-through seen in r7).
// ---------------------------------------------------------------------------

typedef __attribute__((ext_vector_type(8))) short short8v;
typedef __attribute__((ext_vector_type(4))) float float4v;
typedef __attribute__((ext_vector_type(4))) _Float16 half4v;
typedef __attribute__((ext_vector_type(2))) _Float16 half2v;

__device__ inline unsigned short f2bf(float x) {
  unsigned u = __float_as_uint(x);
  return (unsigned short)((u + 0x7FFFu + ((u >> 16) & 1u)) >> 16);
}
__device__ inline float bf2f(unsigned short b) {
  return __uint_as_float(((unsigned)b) << 16);
}

// per-XCD degree histograms: cnt[x][0..N) = odeg, cnt[x][N..2N) = ideg.
// All updaters of copy x run on XCD x -> workgroup-scope atomic is performed
// in that XCD's L2 (cache-resident, no per-atomic write-through).
__global__ __launch_bounds__(256) void k_hist8(const int* __restrict__ src,
                                               const int* __restrict__ dst,
                                               unsigned* __restrict__ cnt,
                                               int N, int E) {
  unsigned xcc;
  asm("s_getreg_b32 %0, hwreg(HW_REG_XCC_ID)" : "=s"(xcc));
  unsigned* my = cnt + (size_t)(xcc & 7) * 2u * (unsigned)N;
  int e = blockIdx.x * 256 + threadIdx.x;
  if (e < E) {
    __hip_atomic_fetch_add(&my[src[e]], 1u, __ATOMIC_RELAXED,
                           __HIP_MEMORY_SCOPE_WORKGROUP);
    __hip_atomic_fetch_add(&my[N + dst[e]], 1u, __ATOMIC_RELAXED,
                           __HIP_MEMORY_SCOPE_WORKGROUP);
  }
}

// sum 8 copies -> degrees; exclusive scan of in-degree -> rowptr partials;
// emit rsqrt norms
__global__ __launch_bounds__(256) void k_scan1_norm(
    const unsigned* __restrict__ cnt, int* __restrict__ part,
    int* __restrict__ bsums, float* __restrict__ nsrc,
    float* __restrict__ ndst, int N) {
  __shared__ int s[256];
  int t = threadIdx.x, g = blockIdx.x * 256 + t;
  int od = 0, id = 0;
  if (g < N) {
#pragma unroll
    for (int x = 0; x < 8; ++x) {
      od += cnt[(size_t)x * 2u * (unsigned)N + g];
      id += cnt[(size_t)x * 2u * (unsigned)N + N + g];
    }
    nsrc[g] = rsqrtf((float)(od + 1)); // +1 self-loop, deg>=1
    ndst[g] = rsqrtf((float)(id + 1));
  }
  int v = (g < N) ? id : 0;
  s[t] = v;
  __syncthreads();
  for (int o = 1; o < 256; o <<= 1) {
    int add = (t >= o) ? s[t - o] : 0;
    __syncthreads();
    s[t] += add;
    __syncthreads();
  }
  if (g < N) part[g] = s[t] - v;
  if (t == 255) bsums[blockIdx.x] = s[255];
}

// requires ceil(N/256) <= 256 (N=50000 -> 196 blocks, OK)
__global__ __launch_bounds__(256) void k_scan2(int* __restrict__ bsums, int nb) {
  __shared__ int s[256];
  int t = threadIdx.x;
  int v = (t < nb) ? bsums[t] : 0;
  s[t] = v;
  __syncthreads();
  for (int o = 1; o < 256; o <<= 1) {
    int add = (t >= o) ? s[t - o] : 0;
    __syncthreads();
    s[t] += add;
    __syncthreads();
  }
  if (t < nb) bsums[t] = s[t] - v;
}

__global__ __launch_bounds__(256) void k_scan3(int* __restrict__ part,
                                               int* __restrict__ cursor,
                                               const int* __restrict__ bsums,
                                               int N, int E) {
  int t = threadIdx.x, g = blockIdx.x * 256 + t;
  if (g < N) {
    int v = part[g] + bsums[blockIdx.x];
    part[g] = v;
    cursor[g] = v;
  }
  if (g == 0) part[N] = E;
}

__global__ __launch_bounds__(256) void k_fill(const int* __restrict__ src,
                                              const int* __restrict__ dst,
                                              int* __restrict__ cursor,
                                              int* __restrict__ colidx, int E) {
  int e = blockIdx.x * 256 + threadIdx.x;
  if (e < E) {
    int s = src[e];
    int p = atomicAdd(&cursor[dst[e]], 1);
    colidx[p] = s;
  }
}

// W [K][NCOL] fp32 -> WtH/WtL [NCOL][K] bf16 (transposed + hi/lo split). K=256.
__global__ __launch_bounds__(256) void k_wsplit(const float* __restrict__ W,
                                                short* __restrict__ WtH,
                                                short* __restrict__ WtL,
                                                int NCOL) {
  const int K = 256;
  int idx = blockIdx.x * 256 + threadIdx.x;
  if (idx >= K * NCOL) return;
  int k = idx & (K - 1);
  int n = idx >> 8;
  float v = W[(size_t)k * NCOL + n];
  unsigned short h = f2bf(v);
  unsigned short l = f2bf(v - bf2f(h));
  WtH[(size_t)n * K + k] = (short)h;
  WtL[(size_t)n * K + k] = (short)l;
}

// out[m,:] = fp16((A[m,:] @ W) * norm[m]); A fp32 [M][256], W pre-split.
// BM=64 rows/block, full NCOL width. bf16 hi/lo split -> 3 MFMA per tile.
// A/B fragments share the same (lane,k) map (within-K permutation cancels);
// D map col=lane&15, row=(lane>>4)*4+j (m89-verified).
template <int NCOL>
__global__ __launch_bounds__(256) void k_gemm_mfma(
    const float* __restrict__ A, const short* __restrict__ WtH,
    const short* __restrict__ WtL, const float* __restrict__ norm,
    _Float16* __restrict__ out, int M) {
  constexpr int K = 256, BM = 64, BK = 32, PAD = 40, NF = NCOL / 16;
  __shared__ short AH[BM][PAD], AL[BM][PAD];
  __shared__ short BH[NCOL][PAD], BL[NCOL][PAD];
  int tid = threadIdx.x;
  int w = tid >> 6, l = tid & 63;
  int lg = l >> 4, ln = l & 15;
  int row0 = blockIdx.x * BM;

  float4v acc[NF];
#pragma unroll
  for (int i = 0; i < NF; ++i) acc[i] = (float4v){0.f, 0.f, 0.f, 0.f};

  int ar = tid >> 2;        // A-stage row 0..63
  int akq = (tid & 3) * 8;  // A-stage k offset 0/8/16/24

  for (int k0 = 0; k0 < K; k0 += BK) {
    // ---- stage A tile: fp32 -> bf16 hi/lo ----
    float av[8];
    int grow = row0 + ar;
    if (grow < M) {
      const float4* ap =
          reinterpret_cast<const float4*>(&A[(size_t)grow * K + k0 + akq]);
      float4 v0 = ap[0], v1 = ap[1];
      av[0] = v0.x; av[1] = v0.y; av[2] = v0.z; av[3] = v0.w;
      av[4] = v1.x; av[5] = v1.y; av[6] = v1.z; av[7] = v1.w;
    } else {
#pragma unroll
      for (int i = 0; i < 8; ++i) av[i] = 0.f;
    }
    short hh[8], ll[8];
#pragma unroll
    for (int i = 0; i < 8; ++i) {
      unsigned short h = f2bf(av[i]);
      hh[i] = (short)h;
      ll[i] = (short)f2bf(av[i] - bf2f(h));
    }
    *reinterpret_cast<short8v*>(&AH[ar][akq]) = *reinterpret_cast<short8v*>(hh);
    *reinterpret_cast<short8v*>(&AL[ar][akq]) = *reinterpret_cast<short8v*>(ll);

    // ---- stage B tile: NCOL rows x 32 k, bf16 pre-split, 16B chunks ----
#pragma unroll
    for (int c = 0; c < NCOL / 64; ++c) {
      int chunk = c * 256 + tid;
      int bn = chunk >> 2, q = (chunk & 3) * 8;
      *reinterpret_cast<short8v*>(&BH[bn][q]) =
          *reinterpret_cast<const short8v*>(&WtH[(size_t)bn * K + k0 + q]);
      *reinterpret_cast<short8v*>(&BL[bn][q]) =
          *reinterpret_cast<const short8v*>(&WtL[(size_t)bn * K + k0 + q]);
    }
    __syncthreads();

    // ---- MFMA ----
    short8v aH = *reinterpret_cast<short8v*>(&AH[w * 16 + ln][lg * 8]);
    short8v aL = *reinterpret_cast<short8v*>(&AL[w * 16 + ln][lg * 8]);
#pragma unroll
    for (int nf = 0; nf < NF; ++nf) {
      short8v bHv = *reinterpret_cast<short8v*>(&BH[nf * 16 + ln][lg * 8]);
      short8v bLv = *reinterpret_cast<short8v*>(&BL[nf * 16 + ln][lg * 8]);
      acc[nf] = __builtin_amdgcn_mfma_f32_16x16x32_bf16(aH, bHv, acc[nf], 0, 0, 0);
      acc[nf] = __builtin_amdgcn_mfma_f32_16x16x32_bf16(aH, bLv, acc[nf], 0, 0, 0);
      acc[nf] = __builtin_amdgcn_mfma_f32_16x16x32_bf16(aL, bHv, acc[nf], 0, 0, 0);
    }
    __syncthreads();
  }

  // ---- epilogue: scale by norm[row], store fp16 ----
  int rbase = row0 + w * 16 + lg * 4;
  float nrm[4];
#pragma unroll
  for (int j = 0; j < 4; ++j)
    nrm[j] = (rbase + j < M) ? norm[rbase + j] : 0.f;
#pragma unroll
  for (int nf = 0; nf < NF; ++nf) {
#pragma unroll
    for (int j = 0; j < 4; ++j) {
      int r = rbase + j;
      if (r < M)
        out[(size_t)r * NCOL + nf * 16 + ln] = (_Float16)(acc[nf][j] * nrm[j]);
    }
  }
}

// pull aggregation, C=256: one wave/node, lane owns 4 ch (fp16 gather, fp32 acc)
__global__ __launch_bounds__(256) void k_agg256(
    const _Float16* __restrict__ h, const int* __restrict__ rowptr,
    const int* __restrict__ colidx, const float* __restrict__ nd,
    const float* __restrict__ bias, float* __restrict__ out, int N) {
  int node = blockIdx.x * 4 + (threadIdx.x >> 6);
  int lane = threadIdx.x & 63;
  if (node >= N) return;
  const half4v* hv = reinterpret_cast<const half4v*>(h);
  half4v hs = hv[(size_t)node * 64 + lane]; // self-loop
  float4 acc;
  acc.x = (float)hs[0]; acc.y = (float)hs[1];
  acc.z = (float)hs[2]; acc.w = (float)hs[3];
  int e0 = rowptr[node], e1 = rowptr[node + 1];
  int e = e0;
  for (; e + 7 < e1; e += 8) {
    int si[8];
#pragma unroll
    for (int i = 0; i < 8; ++i) si[i] = colidx[e + i];
    half4v v[8];
#pragma unroll
    for (int i = 0; i < 8; ++i) v[i] = hv[(size_t)si[i] * 64 + lane];
#pragma unroll
    for (int i = 0; i < 8; ++i) {
      acc.x += (float)v[i][0]; acc.y += (float)v[i][1];
      acc.z += (float)v[i][2]; acc.w += (float)v[i][3];
    }
  }
  for (; e < e1; ++e) {
    half4v v0 = hv[(size_t)colidx[e] * 64 + lane];
    acc.x += (float)v0[0]; acc.y += (float)v0[1];
    acc.z += (float)v0[2]; acc.w += (float)v0[3];
  }
  float n = nd[node];
  float4 b = reinterpret_cast<const float4*>(bias)[lane];
  float4 r;
  r.x = fmaxf(fmaf(acc.x, n, b.x), 0.f);
  r.y = fmaxf(fmaf(acc.y, n, b.y), 0.f);
  r.z = fmaxf(fmaf(acc.z, n, b.z), 0.f);
  r.w = fmaxf(fmaf(acc.w, n, b.w), 0.f);
  reinterpret_cast<float4*>(out)[(size_t)node * 64 + lane] = r;
}

// pull aggregation, C=128: one wave/node, lane owns 2 ch (fp16 gather, fp32 acc)
__global__ __launch_bounds__(256) void k_agg128(
    const _Float16* __restrict__ h, const int* __restrict__ rowptr,
    const int* __restrict__ colidx, const float* __restrict__ nd,
    const float* __restrict__ bias, float* __restrict__ out, int N) {
  int node = blockIdx.x * 4 + (threadIdx.x >> 6);
  int lane = threadIdx.x & 63;
  if (node >= N) return;
  const half2v* hv = reinterpret_cast<const half2v*>(h);
  half2v hs = hv[(size_t)node * 64 + lane]; // self-loop
  float2 acc;
  acc.x = (float)hs[0]; acc.y = (float)hs[1];
  int e0 = rowptr[node], e1 = rowptr[node + 1];
  int e = e0;
  for (; e + 7 < e1; e += 8) {
    int si[8];
#pragma unroll
    for (int i = 0; i < 8; ++i) si[i] = colidx[e + i];
    half2v v[8];
#pragma unroll
    for (int i = 0; i < 8; ++i) v[i] = hv[(size_t)si[i] * 64 + lane];
#pragma unroll
    for (int i = 0; i < 8; ++i) {
      acc.x += (float)v[i][0]; acc.y += (float)v[i][1];
    }
  }
  for (; e < e1; ++e) {
    half2v v0 = hv[(size_t)colidx[e] * 64 + lane];
    acc.x += (float)v0[0]; acc.y += (float)v0[1];
  }
  float n = nd[node];
  float2 b = reinterpret_cast<const float2*>(bias)[lane];
  float2 r;
  r.x = fmaxf(fmaf(acc.x, n, b.x), 0.f);
  r.y = fmaxf(fmaf(acc.y, n, b.y), 0.f);
  reinterpret_cast<float2*>(out)[(size_t)node * 64 + lane] = r;
}

extern "C" void kernel_launch(void* const* d_in, const int* in_sizes, int n_in,
                              void* d_out, int out_size, void* d_ws, size_t ws_size,
                              hipStream_t stream) {
  const float* feats = (const float*)d_in[0];
  const int* src = (const int*)d_in[1];
  const int* dst = (const int*)d_in[2];
  const float* W0 = (const float*)d_in[3];
  const float* b0 = (const float*)d_in[4];
  const float* W1 = (const float*)d_in[5];
  const float* b1 = (const float*)d_in[6];
  float* out = (float*)d_out;

  const int IN_CH = 256, HID = 256, OUT_CH = 128;
  int N = in_sizes[0] / IN_CH;
  int E = in_sizes[1];

  char* ws = (char*)d_ws;
  size_t off = 0;
  auto alloc = [&](size_t bytes) -> void* {
    void* p = ws + off;
    off += (bytes + 255) & ~(size_t)255;
    return p;
  };
  _Float16* h0 = (_Float16*)alloc((size_t)N * HID * 2); // layer-0 GEMM out, fp16
  float* x1     = (float*)alloc((size_t)N * HID * 4);   // layer-0 agg out, fp32
  float* nsrc   = (float*)alloc((size_t)N * 4);
  float* ndst   = (float*)alloc((size_t)N * 4);
  unsigned* cnt = (unsigned*)alloc((size_t)8 * 2 * N * 4); // 8 per-XCD copies
  int*   rowptr = (int*)alloc((size_t)(N + 1) * 4);
  int*   cursor = (int*)alloc((size_t)N * 4);
  int*   colidx = (int*)alloc((size_t)E * 4);
  int*   bsums  = (int*)alloc(1024);
  short* w0h    = (short*)alloc((size_t)HID * IN_CH * 2);
  short* w0l    = (short*)alloc((size_t)HID * IN_CH * 2);
  short* w1h    = (short*)alloc((size_t)OUT_CH * HID * 2);
  short* w1l    = (short*)alloc((size_t)OUT_CH * HID * 2);
  _Float16* h1  = h0; // reuse: h0 dead after k_agg256

  hipMemsetAsync(cnt, 0, (size_t)8 * 2 * N * 4, stream);

  int nbE = (E + 255) / 256, nbN = (N + 255) / 256;
  k_hist8<<<nbE, 256, 0, stream>>>(src, dst, cnt, N, E);
  k_scan1_norm<<<nbN, 256, 0, stream>>>(cnt, rowptr, bsums, nsrc, ndst, N);
  k_scan2<<<1, 256, 0, stream>>>(bsums, nbN);
  k_scan3<<<nbN, 256, 0, stream>>>(rowptr, cursor, bsums, N, E);
  k_fill<<<nbE, 256, 0, stream>>>(src, dst, cursor, colidx, E);

  // weight transpose + bf16 split (K=256 for both layers)
  k_wsplit<<<(IN_CH * HID) / 256, 256, 0, stream>>>(W0, w0h, w0l, HID);
  k_wsplit<<<(HID * OUT_CH) / 256, 256, 0, stream>>>(W1, w1h, w1l, OUT_CH);

  int gm = (N + 63) / 64;
  k_gemm_mfma<256><<<gm, 256, 0, stream>>>(feats, w0h, w0l, nsrc, h0, N);
  k_agg256<<<(N + 3) / 4, 256, 0, stream>>>(h0, rowptr, colidx, ndst, b0, x1, N);

  k_gemm_mfma<128><<<gm, 256, 0, stream>>>(x1, w1h, w1l, nsrc, h1, N);
  k_agg128<<<(N + 3) / 4, 256, 0, stream>>>(h1, rowptr, colidx, ndst, b1, out, N);
}